// Round 10
// baseline (127.837 us; speedup 1.0000x reference)
//
#include <hip/hip_runtime.h>
#include <math.h>

#define H 8
#define B 8
#define C 512
#define L 1024
#define D 64
#define LDK 72    // padded LDS stride for conv staging
#define LDKF 68   // padded f32 stride for flash epilogue bounce

typedef __attribute__((ext_vector_type(4))) float f32x4;
typedef __attribute__((ext_vector_type(8))) short bf16x8;

static __device__ __forceinline__ short f2bf(float x) {      // RNE
    union { float f; unsigned u; } v; v.f = x;
    unsigned r = v.u + 0x7FFFu + ((v.u >> 16) & 1u);
    return (short)(r >> 16);
}
static __device__ __forceinline__ short f2bf_fast(float x) { // round-half-up
    union { float f; unsigned u; } v; v.f = x;
    return (short)((v.u + 0x8000u) >> 16);
}
static __device__ __forceinline__ int pack2(short a, short b) {
    return (int)((unsigned short)a | ((unsigned)(unsigned short)b << 16));
}
static __device__ __forceinline__ float bfs2f(short v) {
    union { unsigned u; float f; } w; w.u = ((unsigned)(unsigned short)v) << 16;
    return w.f;
}
// async 16B/lane global->LDS DMA; lds base must be wave-uniform.
static __device__ __forceinline__ void async16(const void* g, void* s) {
    __builtin_amdgcn_global_load_lds(
        (const __attribute__((address_space(1))) int*)g,
        (__attribute__((address_space(3))) int*)s, 16, 0, 0);
}

// ---------------------------------------------------------------------------
// Staging-transpose helper: x tile -> xT[p][j] bf16, p = l0-1 .. l0+64.
// R10: rows per thread are 16 apart (p = 1+seg+16r, scalar loads) instead of
// consecutive (p = 1+4seg+r, float4) — write banks go 4-distinct/16-way ->
// 16-distinct/4-way (R4 counter: 3.35M SQ_LDS_BANK_CONFLICT localized here).
// Loads stay 64B-contiguous per 16-lane group; same values, same f2bf.
// ---------------------------------------------------------------------------
static __device__ __forceinline__ void stage_xT(
    const float* __restrict__ x, const float* __restrict__ xb,
    short* __restrict__ xT, int b, int h, int l0, int tid)
{
    #pragma unroll
    for (int s = 0; s < 4; s++) {
        int idx = tid + s * 256;             // < 1024
        int j = idx >> 4, seg = idx & 15;
        #pragma unroll
        for (int r = 0; r < 4; r++) {
            float v = xb[j * L + seg + r * 16];
            xT[(1 + seg + r * 16) * LDK + j] = f2bf(v);
        }
    }
    if (tid < 64) {                          // p=0 (reflect left)
        int gl = (l0 == 0) ? 1 : (l0 - 1);
        xT[0 * LDK + tid] = f2bf(x[(size_t)(b * C + h * 64 + tid) * L + gl]);
    } else if (tid < 128) {                  // p=65 (reflect right)
        int j2 = tid - 64;
        int gl = (l0 + 64 >= L) ? (L - 2) : (l0 + 64);
        xT[65 * LDK + j2] = f2bf(x[(size_t)(b * C + h * 64 + j2) * L + gl]);
    }
}

// ---------------------------------------------------------------------------
// Weight prep -> bf16 A-fragment order [((conv*8+h)*3+t)*2+khalf][d][quad][jj].
// wq additionally scaled by (1/sqrt(H))*log2(e) so flash softmax runs in exp2.
// (R7 lesson: inlining this into conv/flash is a net loss — per-lane w rows
// are uncoalesced and the f2bf chain serializes at block head x1024 blocks.)
// ---------------------------------------------------------------------------
__global__ __launch_bounds__(256) void wprep_kernel(
    const float* __restrict__ wq, const float* __restrict__ wk,
    const float* __restrict__ wv, short* __restrict__ wtg)
{
    int idx = blockIdx.x * 256 + threadIdx.x;       // < 294912
    int jj    = idx & 7;
    int quad  = (idx >> 3) & 3;
    int d     = (idx >> 5) & 63;
    int r     = idx >> 11;
    int khalf = r & 1;  r >>= 1;
    int t     = r % 3;  r /= 3;
    int h     = r & 7;
    int conv  = r >> 3;
    const float* w = (conv == 0) ? wq : (conv == 1) ? wk : wv;
    int j_in = khalf * 32 + quad * 8 + jj;
    float v = w[(h * 64 + d) * 192 + j_in * 3 + t];
    if (conv == 0) v *= 0.51012254f;                // (1/sqrt(8)) * log2(e)
    wtg[idx] = f2bf(v);
}

// ---------------------------------------------------------------------------
// Grouped conv1d (K and V only) as bf16 MFMA, k -> kh + vh.
// Outputs in flash's LDS-image order (64 rows x 8 chunks(16B), chunk ^= row&7).
// XCD-affinity: all tiles of bh on XCD bh&7.
// ---------------------------------------------------------------------------
__global__ __launch_bounds__(256) void conv_kv_kernel(
    const float* __restrict__ k, const short* __restrict__ wtg,
    short* __restrict__ kh, short* __restrict__ vh)
{
    int bx   = blockIdx.x;               // < 1024
    int xcd  = bx & 7;
    int g    = bx >> 3;                  // 0..127
    int bh   = xcd + 8 * (g & 7);        // b*H + h, stays on XCD bh&7
    int tile = g >> 3;                   // 0..15
    int h    = bh & 7;
    int b    = bh >> 3;

    __shared__ __align__(16) short xT[66 * LDK];   // [p][j], p = l0-1 .. l0+64

    int l0  = tile * 64;
    int tid = threadIdx.x;
    int wave = tid >> 6, lane = tid & 63;
    int n = lane & 15, quad = lane >> 4;

    const float* xb = k + (size_t)(b * C + h * 64) * L + l0;

    const short* wb0 = wtg + (size_t)((1 * 8 + h) * 6) * 2048;  // k-weights
    const short* wb1 = wtg + (size_t)((2 * 8 + h) * 6) * 2048;  // v-weights
    bf16x8 wf[3][2], wf2[3][2];
    #pragma unroll
    for (int t = 0; t < 3; t++)
        #pragma unroll
        for (int kk = 0; kk < 2; kk++) {
            wf[t][kk]  = *(const bf16x8*)(wb0 + (t * 2 + kk) * 2048
                                          + (wave * 16 + n) * 32 + quad * 8);
            wf2[t][kk] = *(const bf16x8*)(wb1 + (t * 2 + kk) * 2048
                                          + (wave * 16 + n) * 32 + quad * 8);
        }

    stage_xT(k, xb, xT, b, h, l0, tid);
    __syncthreads();

    f32x4 acc[4], acc2[4];
    #pragma unroll
    for (int bl = 0; bl < 4; bl++) {
        acc[bl]  = (f32x4){0.f, 0.f, 0.f, 0.f};
        acc2[bl] = (f32x4){0.f, 0.f, 0.f, 0.f};
    }

    #pragma unroll
    for (int bl = 0; bl < 4; bl++)
        #pragma unroll
        for (int t = 0; t < 3; t++)
            #pragma unroll
            for (int kk = 0; kk < 2; kk++) {
                bf16x8 bf = *(const bf16x8*)&xT[(bl * 16 + n + t) * LDK
                                                + kk * 32 + quad * 8];
                acc[bl]  = __builtin_amdgcn_mfma_f32_16x16x32_bf16(
                    wf[t][kk],  bf, acc[bl],  0, 0, 0);
                acc2[bl] = __builtin_amdgcn_mfma_f32_16x16x32_bf16(
                    wf2[t][kk], bf, acc2[bl], 0, 0, 0);
            }

    {   // kh: rows = l, chunks over d
        short* ob = kh + ((size_t)(bh * 16 + tile)) * 4096;
        int ch = wave * 2 + (quad >> 1);             // logical d-chunk
        #pragma unroll
        for (int bl = 0; bl < 4; bl++) {
            int l = bl * 16 + n;
            int phys = ch ^ (l & 7);
            int2 v;
            v.x = pack2(f2bf(acc[bl][0]), f2bf(acc[bl][1]));
            v.y = pack2(f2bf(acc[bl][2]), f2bf(acc[bl][3]));
            *(int2*)&ob[l * 64 + phys * 8 + (quad & 1) * 4] = v;
        }
    }
    // vh: rows = d, chunks over l; bounce via xT -> int4 stores
    __syncthreads();                 // all waves done with xT B-frags
    #pragma unroll
    for (int bl = 0; bl < 4; bl++)
        #pragma unroll
        for (int r = 0; r < 4; r++) {
            int d = wave * 16 + quad * 4 + r;
            int l = bl * 16 + n;
            int phys = (bl * 2 + (n >> 3)) ^ (d & 7);
            xT[d * 64 + phys * 8 + (n & 7)] = f2bf(acc2[bl][r]);
        }
    __syncthreads();
    short* vb = vh + ((size_t)(bh * 16 + tile)) * 4096;
    #pragma unroll
    for (int jj = 0; jj < 2; jj++) {
        int i = tid + jj * 256;      // < 512
        *(int4*)(vb + i * 8) = *(const int4*)&xT[i * 8];
    }
}

// ---------------------------------------------------------------------------
// Causal flash attention with integrated Q-conv prologue and fused
// residual-add epilogue (ot = bf16(o/L + q), [B,C,L]). K0/V0 DMA issued
// into buffer 1 as the first memory ops (hides under Q-conv prologue);
// tile kt lives in buffer (kt+1)&1, prefetch of kt+1 targets buffer kt&1.
// LDS 40KB: [Q/P 8K][buf0 16K][buf1 16K].
// ---------------------------------------------------------------------------
__global__ __launch_bounds__(256, 4) void flash_kernel(
    const float* __restrict__ q, const short* __restrict__ wtg,
    const short* __restrict__ kh, const short* __restrict__ vh,
    short* __restrict__ ot)
{
    __shared__ __align__(16) short lds[20480];
    short* xT = &lds[4096];              // Q-conv staging (4752 shorts, buf0)

    int bx  = blockIdx.x;                // < 1024
    int xcd = bx & 7;
    int g   = bx >> 3;                   // 0..127
    int bh  = xcd + 8 * (g & 7);         // same XCD as conv's bh blocks
    int qt  = 15 - (g >> 3);             // heavy tiles dispatch first
    int h  = bh & 7, b = bh >> 3;

    int tid  = threadIdx.x;
    int wave = tid >> 6, lane = tid & 63;
    int n    = lane & 15, quad = lane >> 4;
    int l0   = qt * 64;

    const short* Kbase = kh + (size_t)bh * 65536;
    const short* Vbase = vh + (size_t)bh * 65536;

    // ======== issue K0/V0 DMA into buffer 1 FIRST (hides under Q-conv) =====
    {
        int ci = wave * 64 + lane;
        async16((const int4*)Kbase + ci,        lds + 12288 + wave * 512);
        async16((const int4*)Kbase + ci + 256,  lds + 12288 + 2048 + wave * 512);
        async16((const int4*)Vbase + ci,        lds + 16384 + wave * 512);
        async16((const int4*)Vbase + ci + 256,  lds + 16384 + 2048 + wave * 512);
    }

    // ======== Q-conv prologue: q tile qt -> LDS Q-image at lds[0..4096) =====
    {
        const float* xb = q + (size_t)(b * C + h * 64) * L + l0;
        const short* wb0 = wtg + (size_t)((0 * 8 + h) * 6) * 2048;  // q-weights
        bf16x8 wf[3][2];
        #pragma unroll
        for (int t = 0; t < 3; t++)
            #pragma unroll
            for (int kk = 0; kk < 2; kk++)
                wf[t][kk] = *(const bf16x8*)(wb0 + (t * 2 + kk) * 2048
                                             + (wave * 16 + n) * 32 + quad * 8);
        stage_xT(q, xb, xT, b, h, l0, tid);
        __syncthreads();

        f32x4 acc[4];
        #pragma unroll
        for (int bl = 0; bl < 4; bl++) acc[bl] = (f32x4){0.f, 0.f, 0.f, 0.f};
        #pragma unroll
        for (int bl = 0; bl < 4; bl++)
            #pragma unroll
            for (int t = 0; t < 3; t++)
                #pragma unroll
                for (int kk = 0; kk < 2; kk++) {
                    bf16x8 bf = *(const bf16x8*)&xT[(bl * 16 + n + t) * LDK
                                                    + kk * 32 + quad * 8];
                    acc[bl] = __builtin_amdgcn_mfma_f32_16x16x32_bf16(
                        wf[t][kk], bf, acc[bl], 0, 0, 0);
                }
        // no barrier: Q-image (lds[0..4096)) is disjoint from xT and rows
        // are wave-private; tile-1 prefetch into xT region is ordered by
        // the pre-loop barrier below.
        int ch = wave * 2 + (quad >> 1);
        #pragma unroll
        for (int bl = 0; bl < 4; bl++) {
            int l = bl * 16 + n;
            int phys = ch ^ (l & 7);
            int2 v;
            v.x = pack2(f2bf(acc[bl][0]), f2bf(acc[bl][1]));
            v.y = pack2(f2bf(acc[bl][2]), f2bf(acc[bl][3]));
            *(int2*)&lds[l * 64 + phys * 8 + (quad & 1) * 4] = v;
        }
    }

    __syncthreads();                     // K0/V0 landed (vmcnt0) + Q-image +
                                         // all xT reads complete

    int ph0 = quad ^ (n & 7);            // phys chunk for logical chunk quad
    int ph1 = (quad + 4) ^ (n & 7);      // ... for logical chunk quad+4

    bf16x8 qa0 = *(const bf16x8*)&lds[(wave * 16 + n) * 64 + ph0 * 8];
    bf16x8 qa1 = *(const bf16x8*)&lds[(wave * 16 + n) * 64 + ph1 * 8];

    const bf16x8 ones = {16256,16256,16256,16256,16256,16256,16256,16256};

    f32x4 O0 = {0.f,0.f,0.f,0.f}, O1 = O0, O2 = O0, O3 = O0;
    f32x4 Lacc = {0.f,0.f,0.f,0.f};

    // P-write addressing (fixed per lane): row = wave*16+n, key base = quad*4
    int prow   = wave * 16 + n;
    int pswz   = n & 7;

    for (int kt = 0; kt <= qt; kt++) {
        if (kt > 0) __syncthreads();     // my kt-loads drained; all past kt-1 reads
        if (kt < qt) {                   // prefetch kt+1 into the other buffer
            const short* Kg = Kbase + (size_t)(kt + 1) * 4096;
            const short* Vg = Vbase + (size_t)(kt + 1) * 4096;
            int koff = 4096 + (kt & 1) * 8192;   // buffer for tile kt+1
            int ci = wave * 64 + lane;
            async16((const int4*)Kg + ci,       lds + koff + wave * 512);
            async16((const int4*)Kg + ci + 256, lds + koff + 2048 + wave * 512);
            async16((const int4*)Vg + ci,       lds + koff + 4096 + wave * 512);
            async16((const int4*)Vg + ci + 256, lds + koff + 4096 + 2048 + wave * 512);
        }
        const short* Kb = lds + 4096 + (((kt + 1) & 1)) * 8192;
        const short* Vb = Kb + 4096;

        // S^T = K.Q^T (log2 domain; wq pre-scaled). A = K-frag, B = Q-frag.
        f32x4 s[4];
        #pragma unroll
        for (int bk = 0; bk < 4; bk++) {
            int row = bk * 16 + n;
            bf16x8 kb0 = *(const bf16x8*)&Kb[row * 64 + ph0 * 8];
            bf16x8 kb1 = *(const bf16x8*)&Kb[row * 64 + ph1 * 8];
            f32x4 acc = {0.f,0.f,0.f,0.f};
            acc = __builtin_amdgcn_mfma_f32_16x16x32_bf16(kb0, qa0, acc, 0, 0, 0);
            acc = __builtin_amdgcn_mfma_f32_16x16x32_bf16(kb1, qa1, acc, 0, 0, 0);
            s[bk] = acc;
        }

        if (kt == qt) {                  // causal mask on diagonal tile
            #pragma unroll
            for (int bk = 0; bk < 4; bk++)
                #pragma unroll
                for (int r = 0; r < 4; r++)
                    if (bk * 16 + quad * 4 + r > wave * 16 + n)
                        s[bk][r] = -INFINITY;
        }

        // p = exp2(s - 20) -> P[qrow][key]: 4 packed b64 writes per lane
        #pragma unroll
        for (int bk = 0; bk < 4; bk++) {
            int pch = (bk * 2 + (quad >> 1)) ^ pswz;
            int2 v;
            v.x = pack2(f2bf_fast(__builtin_amdgcn_exp2f(s[bk][0] - 20.f)),
                        f2bf_fast(__builtin_amdgcn_exp2f(s[bk][1] - 20.f)));
            v.y = pack2(f2bf_fast(__builtin_amdgcn_exp2f(s[bk][2] - 20.f)),
                        f2bf_fast(__builtin_amdgcn_exp2f(s[bk][3] - 20.f)));
            *(int2*)&lds[prow * 64 + pch * 8 + (quad & 1) * 4] = v;
        }

        bf16x8 pa0 = *(const bf16x8*)&lds[prow * 64 + ph0 * 8];
        bf16x8 pa1 = *(const bf16x8*)&lds[prow * 64 + ph1 * 8];

        // li += P . 1
        Lacc = __builtin_amdgcn_mfma_f32_16x16x32_bf16(pa0, ones, Lacc, 0, 0, 0);
        Lacc = __builtin_amdgcn_mfma_f32_16x16x32_bf16(pa1, ones, Lacc, 0, 0, 0);

        // O += P V
        #pragma unroll
        for (int bk = 0; bk < 4; bk++) {
            int row = bk * 16 + n;
            bf16x8 v0 = *(const bf16x8*)&Vb[row * 64 + ph0 * 8];
            bf16x8 v1 = *(const bf16x8*)&Vb[row * 64 + ph1 * 8];
            f32x4* Op = (bk == 0) ? &O0 : (bk == 1) ? &O1 : (bk == 2) ? &O2 : &O3;
            *Op = __builtin_amdgcn_mfma_f32_16x16x32_bf16(pa0, v0, *Op, 0, 0, 0);
            *Op = __builtin_amdgcn_mfma_f32_16x16x32_bf16(pa1, v1, *Op, 0, 0, 0);
        }
    }

    // epilogue: f32 transpose bounce, + residual q, single RNE rounding ->
    // ot[B, C, L] bf16 (x = o/L + q; ln reads ot only)
    float inv[4];
    #pragma unroll
    for (int r = 0; r < 4; r++) inv[r] = 1.f / Lacc[r];

    __syncthreads();                     // everyone done with K/V buffers
    float* Ebf = (float*)(lds + 4096);   // [d 64][l 64] stride LDKF, 17.4 KB
    #pragma unroll
    for (int bk = 0; bk < 4; bk++) {
        f32x4* Op = (bk == 0) ? &O0 : (bk == 1) ? &O1 : (bk == 2) ? &O2 : &O3;
        #pragma unroll
        for (int r = 0; r < 4; r++)
            Ebf[(bk * 16 + n) * LDKF + wave * 16 + quad * 4 + r] =
                (*Op)[r] * inv[r];
    }
    __syncthreads();
    #pragma unroll
    for (int jj = 0; jj < 2; jj++) {
        int i = tid + jj * 256;          // < 512
        int d = i >> 3, seg = i & 7;
        const float* Ef = &Ebf[d * LDKF + seg * 8];
        const float* qp = q + ((size_t)(b * C) + h * 64 + d) * L + qt * 64 + seg * 8;
        float4 o0 = *(const float4*)Ef;
        float4 o1 = *(const float4*)(Ef + 4);
        float4 q0 = *(const float4*)qp;
        float4 q1 = *(const float4*)(qp + 4);
        int4 v;
        v.x = pack2(f2bf(o0.x + q0.x), f2bf(o0.y + q0.y));
        v.y = pack2(f2bf(o0.z + q0.z), f2bf(o0.w + q0.w));
        v.z = pack2(f2bf(o1.x + q1.x), f2bf(o1.y + q1.y));
        v.w = pack2(f2bf(o1.z + q1.z), f2bf(o1.w + q1.w));
        *(int4*)(ot + ((size_t)(b * C) + h * 64 + d) * L + qt * 64 + seg * 8) = v;
    }
}

// ---------------------------------------------------------------------------
// LayerNorm over channels, single pass, coalesced along L. Residual already
// folded into ot by flash -> reads ot only (no q). R0 block structure
// (best of three measured variants; ln resists vectorization/TLP changes).
// ---------------------------------------------------------------------------
__global__ __launch_bounds__(512) void ln_kernel(
    const short* __restrict__ ot,
    const float* __restrict__ gamma, const float* __restrict__ beta,
    float* __restrict__ y)
{
    int bx = blockIdx.x;
    int tile = bx & 31;                  // L/32
    int b = bx >> 5;
    int l0 = tile * 32;
    int tid = threadIdx.x;
    int li_ = tid & 31, cs = tid >> 5;   // cs in 0..15, 32 channels each

    __shared__ float sp[16][33], ssp[16][33];
    __shared__ float mu_s[32], rs_s[32];

    size_t base = ((size_t)b * C + cs * 32) * L + l0 + li_;
    const short* otp = ot + base;

    float xr[32];
    float s = 0.f, ss = 0.f;
    #pragma unroll
    for (int cc = 0; cc < 32; cc++) {
        float x = bfs2f(otp[(size_t)cc * L]);
        xr[cc] = x;
        s += x; ss += x * x;
    }
    sp[cs][li_] = s; ssp[cs][li_] = ss;
    __syncthreads();
    if (tid < 32) {
        float t1 = 0.f, t2 = 0.f;
        #pragma unroll
        for (int j = 0; j < 16; j++) { t1 += sp[j][tid]; t2 += ssp[j][tid]; }
        float mean = t1 * (1.f / 512.f);
        float var  = t2 * (1.f / 512.f) - mean * mean;
        mu_s[tid] = mean;
        rs_s[tid] = rsqrtf(var + 1e-5f);
    }
    __syncthreads();
    float mu = mu_s[li_], rs = rs_s[li_];
    float* yp = y + base;
    #pragma unroll
    for (int cc = 0; cc < 32; cc++) {
        int c = cs * 32 + cc;
        yp[(size_t)cc * L] = (xr[cc] - mu) * rs * gamma[c] + beta[c];
    }
}

// ---------------------------------------------------------------------------
extern "C" void kernel_launch(void* const* d_in, const int* in_sizes, int n_in,
                              void* d_out, int out_size, void* d_ws, size_t ws_size,
                              hipStream_t stream)
{
    const float* q     = (const float*)d_in[0];
    const float* k     = (const float*)d_in[1];
    // d_in[2] = mask — analytic
    const float* wq    = (const float*)d_in[3];
    const float* wk    = (const float*)d_in[4];
    const float* wv    = (const float*)d_in[5];
    const float* gamma = (const float*)d_in[6];
    const float* beta  = (const float*)d_in[7];
    float* y = (float*)d_out;

    const size_t N = (size_t)B * H * L * D;      // 4,194,304
    short* kh  = (short*)d_ws;                   // [BH][16][64 rows][8-chunk swz]
    short* vh  = kh + N;                         // [BH][16][d 64][l-chunk swz]
    short* ot  = vh + N;                         // [B, C, L] bf16 (o/L + q)
    short* wtg = ot + N;                         // 294912 bf16 A-frag weights

    wprep_kernel<<<1152, 256, 0, stream>>>(wq, wk, wv, wtg);
    conv_kv_kernel<<<B * H * (L / 64), 256, 0, stream>>>(k, wtg, kh, vh);
    flash_kernel<<<B * H * (L / 64), 256, 0, stream>>>(q, wtg, kh, vh, ot);
    ln_kernel<<<B * (L / 32), 512, 0, stream>>>(ot, gamma, beta, y);
}

// Round 11
// 126.090 us; speedup vs baseline: 1.0139x; 1.0139x over previous
//
#include <hip/hip_runtime.h>
#include <math.h>

#define H 8
#define B 8
#define C 512
#define L 1024
#define D 64
#define LDK 72    // padded LDS stride for conv staging
#define LDKF 68   // padded f32 stride for flash epilogue bounce

typedef __attribute__((ext_vector_type(4))) float f32x4;
typedef __attribute__((ext_vector_type(8))) short bf16x8;

static __device__ __forceinline__ short f2bf(float x) {      // RNE
    union { float f; unsigned u; } v; v.f = x;
    unsigned r = v.u + 0x7FFFu + ((v.u >> 16) & 1u);
    return (short)(r >> 16);
}
static __device__ __forceinline__ short f2bf_fast(float x) { // round-half-up
    union { float f; unsigned u; } v; v.f = x;
    return (short)((v.u + 0x8000u) >> 16);
}
static __device__ __forceinline__ int pack2(short a, short b) {
    return (int)((unsigned short)a | ((unsigned)(unsigned short)b << 16));
}
static __device__ __forceinline__ float bfs2f(short v) {
    union { unsigned u; float f; } w; w.u = ((unsigned)(unsigned short)v) << 16;
    return w.f;
}
// async 16B/lane global->LDS DMA; lds base must be wave-uniform.
static __device__ __forceinline__ void async16(const void* g, void* s) {
    __builtin_amdgcn_global_load_lds(
        (const __attribute__((address_space(1))) int*)g,
        (__attribute__((address_space(3))) int*)s, 16, 0, 0);
}

// ---------------------------------------------------------------------------
// Staging-transpose helper: x tile -> xT[p][j] bf16, p = l0-1 .. l0+64.
// float4 loads, consecutive rows per thread (R10 lesson: the 16-way write
// conflict here is TLP-hidden; splitting to scalar loads to fix banks cost
// +1.5us in extra VMEM issue — keep the float4 form).
// ---------------------------------------------------------------------------
static __device__ __forceinline__ void stage_xT(
    const float* __restrict__ x, const float* __restrict__ xb,
    short* __restrict__ xT, int b, int h, int l0, int tid)
{
    #pragma unroll
    for (int s = 0; s < 4; s++) {
        int idx = tid + s * 256;             // < 1024
        int j = idx >> 4, seg = idx & 15;
        float4 v = *(const float4*)(xb + j * L + seg * 4);
        int p = 1 + seg * 4;
        xT[(p + 0) * LDK + j] = f2bf(v.x);
        xT[(p + 1) * LDK + j] = f2bf(v.y);
        xT[(p + 2) * LDK + j] = f2bf(v.z);
        xT[(p + 3) * LDK + j] = f2bf(v.w);
    }
    if (tid < 64) {                          // p=0 (reflect left)
        int gl = (l0 == 0) ? 1 : (l0 - 1);
        xT[0 * LDK + tid] = f2bf(x[(size_t)(b * C + h * 64 + tid) * L + gl]);
    } else if (tid < 128) {                  // p=65 (reflect right)
        int j2 = tid - 64;
        int gl = (l0 + 64 >= L) ? (L - 2) : (l0 + 64);
        xT[65 * LDK + j2] = f2bf(x[(size_t)(b * C + h * 64 + j2) * L + gl]);
    }
}

// ---------------------------------------------------------------------------
// Weight prep -> bf16 A-fragment order [((conv*8+h)*3+t)*2+khalf][d][quad][jj].
// wq additionally scaled by (1/sqrt(H))*log2(e) so flash softmax runs in exp2.
// (R7 lesson: inlining this into conv/flash is a net loss — per-lane w rows
// are uncoalesced and the f2bf chain serializes at block head x1024 blocks.)
// ---------------------------------------------------------------------------
__global__ __launch_bounds__(256) void wprep_kernel(
    const float* __restrict__ wq, const float* __restrict__ wk,
    const float* __restrict__ wv, short* __restrict__ wtg)
{
    int idx = blockIdx.x * 256 + threadIdx.x;       // < 294912
    int jj    = idx & 7;
    int quad  = (idx >> 3) & 3;
    int d     = (idx >> 5) & 63;
    int r     = idx >> 11;
    int khalf = r & 1;  r >>= 1;
    int t     = r % 3;  r /= 3;
    int h     = r & 7;
    int conv  = r >> 3;
    const float* w = (conv == 0) ? wq : (conv == 1) ? wk : wv;
    int j_in = khalf * 32 + quad * 8 + jj;
    float v = w[(h * 64 + d) * 192 + j_in * 3 + t];
    if (conv == 0) v *= 0.51012254f;                // (1/sqrt(8)) * log2(e)
    wtg[idx] = f2bf(v);
}

// ---------------------------------------------------------------------------
// Grouped conv1d (K and V only) as bf16 MFMA, k -> kh + vh.
// Outputs in flash's LDS-image order (64 rows x 8 chunks(16B), chunk ^= row&7).
// XCD-affinity: all tiles of bh on XCD bh&7.
// ---------------------------------------------------------------------------
__global__ __launch_bounds__(256) void conv_kv_kernel(
    const float* __restrict__ k, const short* __restrict__ wtg,
    short* __restrict__ kh, short* __restrict__ vh)
{
    int bx   = blockIdx.x;               // < 1024
    int xcd  = bx & 7;
    int g    = bx >> 3;                  // 0..127
    int bh   = xcd + 8 * (g & 7);        // b*H + h, stays on XCD bh&7
    int tile = g >> 3;                   // 0..15
    int h    = bh & 7;
    int b    = bh >> 3;

    __shared__ __align__(16) short xT[66 * LDK];   // [p][j], p = l0-1 .. l0+64

    int l0  = tile * 64;
    int tid = threadIdx.x;
    int wave = tid >> 6, lane = tid & 63;
    int n = lane & 15, quad = lane >> 4;

    const float* xb = k + (size_t)(b * C + h * 64) * L + l0;

    const short* wb0 = wtg + (size_t)((1 * 8 + h) * 6) * 2048;  // k-weights
    const short* wb1 = wtg + (size_t)((2 * 8 + h) * 6) * 2048;  // v-weights
    bf16x8 wf[3][2], wf2[3][2];
    #pragma unroll
    for (int t = 0; t < 3; t++)
        #pragma unroll
        for (int kk = 0; kk < 2; kk++) {
            wf[t][kk]  = *(const bf16x8*)(wb0 + (t * 2 + kk) * 2048
                                          + (wave * 16 + n) * 32 + quad * 8);
            wf2[t][kk] = *(const bf16x8*)(wb1 + (t * 2 + kk) * 2048
                                          + (wave * 16 + n) * 32 + quad * 8);
        }

    stage_xT(k, xb, xT, b, h, l0, tid);
    __syncthreads();

    f32x4 acc[4], acc2[4];
    #pragma unroll
    for (int bl = 0; bl < 4; bl++) {
        acc[bl]  = (f32x4){0.f, 0.f, 0.f, 0.f};
        acc2[bl] = (f32x4){0.f, 0.f, 0.f, 0.f};
    }

    #pragma unroll
    for (int bl = 0; bl < 4; bl++)
        #pragma unroll
        for (int t = 0; t < 3; t++)
            #pragma unroll
            for (int kk = 0; kk < 2; kk++) {
                bf16x8 bf = *(const bf16x8*)&xT[(bl * 16 + n + t) * LDK
                                                + kk * 32 + quad * 8];
                acc[bl]  = __builtin_amdgcn_mfma_f32_16x16x32_bf16(
                    wf[t][kk],  bf, acc[bl],  0, 0, 0);
                acc2[bl] = __builtin_amdgcn_mfma_f32_16x16x32_bf16(
                    wf2[t][kk], bf, acc2[bl], 0, 0, 0);
            }

    {   // kh: rows = l, chunks over d
        short* ob = kh + ((size_t)(bh * 16 + tile)) * 4096;
        int ch = wave * 2 + (quad >> 1);             // logical d-chunk
        #pragma unroll
        for (int bl = 0; bl < 4; bl++) {
            int l = bl * 16 + n;
            int phys = ch ^ (l & 7);
            int2 v;
            v.x = pack2(f2bf(acc[bl][0]), f2bf(acc[bl][1]));
            v.y = pack2(f2bf(acc[bl][2]), f2bf(acc[bl][3]));
            *(int2*)&ob[l * 64 + phys * 8 + (quad & 1) * 4] = v;
        }
    }
    // vh: rows = d, chunks over l; bounce via xT -> int4 stores
    __syncthreads();                 // all waves done with xT B-frags
    #pragma unroll
    for (int bl = 0; bl < 4; bl++)
        #pragma unroll
        for (int r = 0; r < 4; r++) {
            int d = wave * 16 + quad * 4 + r;
            int l = bl * 16 + n;
            int phys = (bl * 2 + (n >> 3)) ^ (d & 7);
            xT[d * 64 + phys * 8 + (n & 7)] = f2bf(acc2[bl][r]);
        }
    __syncthreads();
    short* vb = vh + ((size_t)(bh * 16 + tile)) * 4096;
    #pragma unroll
    for (int jj = 0; jj < 2; jj++) {
        int i = tid + jj * 256;      // < 512
        *(int4*)(vb + i * 8) = *(const int4*)&xT[i * 8];
    }
}

// ---------------------------------------------------------------------------
// Causal flash attention with integrated Q-conv prologue and fused
// residual-add epilogue (ot = bf16(o/L + q), [B,C,L]). K0/V0 DMA issued
// into buffer 1 as the first memory ops (hides under Q-conv prologue);
// tile kt lives in buffer (kt+1)&1, prefetch of kt+1 targets buffer kt&1.
// LDS 40KB: [Q/P 8K][buf0 16K][buf1 16K].
// ---------------------------------------------------------------------------
__global__ __launch_bounds__(256, 4) void flash_kernel(
    const float* __restrict__ q, const short* __restrict__ wtg,
    const short* __restrict__ kh, const short* __restrict__ vh,
    short* __restrict__ ot)
{
    __shared__ __align__(16) short lds[20480];
    short* xT = &lds[4096];              // Q-conv staging (4752 shorts, buf0)

    int bx  = blockIdx.x;                // < 1024
    int xcd = bx & 7;
    int g   = bx >> 3;                   // 0..127
    int bh  = xcd + 8 * (g & 7);         // same XCD as conv's bh blocks
    int qt  = 15 - (g >> 3);             // heavy tiles dispatch first
    int h  = bh & 7, b = bh >> 3;

    int tid  = threadIdx.x;
    int wave = tid >> 6, lane = tid & 63;
    int n    = lane & 15, quad = lane >> 4;
    int l0   = qt * 64;

    const short* Kbase = kh + (size_t)bh * 65536;
    const short* Vbase = vh + (size_t)bh * 65536;

    // ======== issue K0/V0 DMA into buffer 1 FIRST (hides under Q-conv) =====
    {
        int ci = wave * 64 + lane;
        async16((const int4*)Kbase + ci,        lds + 12288 + wave * 512);
        async16((const int4*)Kbase + ci + 256,  lds + 12288 + 2048 + wave * 512);
        async16((const int4*)Vbase + ci,        lds + 16384 + wave * 512);
        async16((const int4*)Vbase + ci + 256,  lds + 16384 + 2048 + wave * 512);
    }

    // ======== Q-conv prologue: q tile qt -> LDS Q-image at lds[0..4096) =====
    {
        const float* xb = q + (size_t)(b * C + h * 64) * L + l0;
        const short* wb0 = wtg + (size_t)((0 * 8 + h) * 6) * 2048;  // q-weights
        bf16x8 wf[3][2];
        #pragma unroll
        for (int t = 0; t < 3; t++)
            #pragma unroll
            for (int kk = 0; kk < 2; kk++)
                wf[t][kk] = *(const bf16x8*)(wb0 + (t * 2 + kk) * 2048
                                             + (wave * 16 + n) * 32 + quad * 8);
        stage_xT(q, xb, xT, b, h, l0, tid);
        __syncthreads();

        f32x4 acc[4];
        #pragma unroll
        for (int bl = 0; bl < 4; bl++) acc[bl] = (f32x4){0.f, 0.f, 0.f, 0.f};
        #pragma unroll
        for (int bl = 0; bl < 4; bl++)
            #pragma unroll
            for (int t = 0; t < 3; t++)
                #pragma unroll
                for (int kk = 0; kk < 2; kk++) {
                    bf16x8 bf = *(const bf16x8*)&xT[(bl * 16 + n + t) * LDK
                                                    + kk * 32 + quad * 8];
                    acc[bl] = __builtin_amdgcn_mfma_f32_16x16x32_bf16(
                        wf[t][kk], bf, acc[bl], 0, 0, 0);
                }
        // no barrier: Q-image (lds[0..4096)) is disjoint from xT and rows
        // are wave-private; tile-1 prefetch into xT region is ordered by
        // the pre-loop barrier below.
        int ch = wave * 2 + (quad >> 1);
        #pragma unroll
        for (int bl = 0; bl < 4; bl++) {
            int l = bl * 16 + n;
            int phys = ch ^ (l & 7);
            int2 v;
            v.x = pack2(f2bf(acc[bl][0]), f2bf(acc[bl][1]));
            v.y = pack2(f2bf(acc[bl][2]), f2bf(acc[bl][3]));
            *(int2*)&lds[l * 64 + phys * 8 + (quad & 1) * 4] = v;
        }
    }

    __syncthreads();                     // K0/V0 landed (vmcnt0) + Q-image +
                                         // all xT reads complete

    int ph0 = quad ^ (n & 7);            // phys chunk for logical chunk quad
    int ph1 = (quad + 4) ^ (n & 7);      // ... for logical chunk quad+4

    bf16x8 qa0 = *(const bf16x8*)&lds[(wave * 16 + n) * 64 + ph0 * 8];
    bf16x8 qa1 = *(const bf16x8*)&lds[(wave * 16 + n) * 64 + ph1 * 8];

    const bf16x8 ones = {16256,16256,16256,16256,16256,16256,16256,16256};

    f32x4 O0 = {0.f,0.f,0.f,0.f}, O1 = O0, O2 = O0, O3 = O0;
    f32x4 Lacc = {0.f,0.f,0.f,0.f};

    // P-write addressing (fixed per lane): row = wave*16+n, key base = quad*4
    int prow   = wave * 16 + n;
    int pswz   = n & 7;

    for (int kt = 0; kt <= qt; kt++) {
        if (kt > 0) __syncthreads();     // my kt-loads drained; all past kt-1 reads
        if (kt < qt) {                   // prefetch kt+1 into the other buffer
            const short* Kg = Kbase + (size_t)(kt + 1) * 4096;
            const short* Vg = Vbase + (size_t)(kt + 1) * 4096;
            int koff = 4096 + (kt & 1) * 8192;   // buffer for tile kt+1
            int ci = wave * 64 + lane;
            async16((const int4*)Kg + ci,       lds + koff + wave * 512);
            async16((const int4*)Kg + ci + 256, lds + koff + 2048 + wave * 512);
            async16((const int4*)Vg + ci,       lds + koff + 4096 + wave * 512);
            async16((const int4*)Vg + ci + 256, lds + koff + 4096 + 2048 + wave * 512);
        }
        const short* Kb = lds + 4096 + (((kt + 1) & 1)) * 8192;
        const short* Vb = Kb + 4096;

        // S^T = K.Q^T (log2 domain; wq pre-scaled). A = K-frag, B = Q-frag.
        f32x4 s[4];
        #pragma unroll
        for (int bk = 0; bk < 4; bk++) {
            int row = bk * 16 + n;
            bf16x8 kb0 = *(const bf16x8*)&Kb[row * 64 + ph0 * 8];
            bf16x8 kb1 = *(const bf16x8*)&Kb[row * 64 + ph1 * 8];
            f32x4 acc = {0.f,0.f,0.f,0.f};
            acc = __builtin_amdgcn_mfma_f32_16x16x32_bf16(kb0, qa0, acc, 0, 0, 0);
            acc = __builtin_amdgcn_mfma_f32_16x16x32_bf16(kb1, qa1, acc, 0, 0, 0);
            s[bk] = acc;
        }

        if (kt == qt) {                  // causal mask on diagonal tile
            #pragma unroll
            for (int bk = 0; bk < 4; bk++)
                #pragma unroll
                for (int r = 0; r < 4; r++)
                    if (bk * 16 + quad * 4 + r > wave * 16 + n)
                        s[bk][r] = -INFINITY;
        }

        // p = exp2(s - 20) -> P[qrow][key]: 4 packed b64 writes per lane
        #pragma unroll
        for (int bk = 0; bk < 4; bk++) {
            int pch = (bk * 2 + (quad >> 1)) ^ pswz;
            int2 v;
            v.x = pack2(f2bf_fast(__builtin_amdgcn_exp2f(s[bk][0] - 20.f)),
                        f2bf_fast(__builtin_amdgcn_exp2f(s[bk][1] - 20.f)));
            v.y = pack2(f2bf_fast(__builtin_amdgcn_exp2f(s[bk][2] - 20.f)),
                        f2bf_fast(__builtin_amdgcn_exp2f(s[bk][3] - 20.f)));
            *(int2*)&lds[prow * 64 + pch * 8 + (quad & 1) * 4] = v;
        }

        bf16x8 pa0 = *(const bf16x8*)&lds[prow * 64 + ph0 * 8];
        bf16x8 pa1 = *(const bf16x8*)&lds[prow * 64 + ph1 * 8];

        // li += P . 1
        Lacc = __builtin_amdgcn_mfma_f32_16x16x32_bf16(pa0, ones, Lacc, 0, 0, 0);
        Lacc = __builtin_amdgcn_mfma_f32_16x16x32_bf16(pa1, ones, Lacc, 0, 0, 0);

        // O += P V
        #pragma unroll
        for (int bk = 0; bk < 4; bk++) {
            int row = bk * 16 + n;
            bf16x8 v0 = *(const bf16x8*)&Vb[row * 64 + ph0 * 8];
            bf16x8 v1 = *(const bf16x8*)&Vb[row * 64 + ph1 * 8];
            f32x4* Op = (bk == 0) ? &O0 : (bk == 1) ? &O1 : (bk == 2) ? &O2 : &O3;
            *Op = __builtin_amdgcn_mfma_f32_16x16x32_bf16(pa0, v0, *Op, 0, 0, 0);
            *Op = __builtin_amdgcn_mfma_f32_16x16x32_bf16(pa1, v1, *Op, 0, 0, 0);
        }
    }

    // epilogue: f32 transpose bounce, + residual q, single RNE rounding ->
    // ot[B, C, L] bf16 (x = o/L + q; ln reads ot only)
    float inv[4];
    #pragma unroll
    for (int r = 0; r < 4; r++) inv[r] = 1.f / Lacc[r];

    __syncthreads();                     // everyone done with K/V buffers
    float* Ebf = (float*)(lds + 4096);   // [d 64][l 64] stride LDKF, 17.4 KB
    #pragma unroll
    for (int bk = 0; bk < 4; bk++) {
        f32x4* Op = (bk == 0) ? &O0 : (bk == 1) ? &O1 : (bk == 2) ? &O2 : &O3;
        #pragma unroll
        for (int r = 0; r < 4; r++)
            Ebf[(bk * 16 + n) * LDKF + wave * 16 + quad * 4 + r] =
                (*Op)[r] * inv[r];
    }
    __syncthreads();
    #pragma unroll
    for (int jj = 0; jj < 2; jj++) {
        int i = tid + jj * 256;          // < 512
        int d = i >> 3, seg = i & 7;
        const float* Ef = &Ebf[d * LDKF + seg * 8];
        const float* qp = q + ((size_t)(b * C) + h * 64 + d) * L + qt * 64 + seg * 8;
        float4 o0 = *(const float4*)Ef;
        float4 o1 = *(const float4*)(Ef + 4);
        float4 q0 = *(const float4*)qp;
        float4 q1 = *(const float4*)(qp + 4);
        int4 v;
        v.x = pack2(f2bf(o0.x + q0.x), f2bf(o0.y + q0.y));
        v.y = pack2(f2bf(o0.z + q0.z), f2bf(o0.w + q0.w));
        v.z = pack2(f2bf(o1.x + q1.x), f2bf(o1.y + q1.y));
        v.w = pack2(f2bf(o1.z + q1.z), f2bf(o1.w + q1.w));
        *(int4*)(ot + ((size_t)(b * C) + h * 64 + d) * L + qt * 64 + seg * 8) = v;
    }
}

// ---------------------------------------------------------------------------
// LayerNorm over channels, single pass, coalesced along L. Residual already
// folded into ot by flash -> reads ot only (no q). R0 block structure
// (best of three measured variants; ln resists vectorization/TLP changes).
// ---------------------------------------------------------------------------
__global__ __launch_bounds__(512) void ln_kernel(
    const short* __restrict__ ot,
    const float* __restrict__ gamma, const float* __restrict__ beta,
    float* __restrict__ y)
{
    int bx = blockIdx.x;
    int tile = bx & 31;                  // L/32
    int b = bx >> 5;
    int l0 = tile * 32;
    int tid = threadIdx.x;
    int li_ = tid & 31, cs = tid >> 5;   // cs in 0..15, 32 channels each

    __shared__ float sp[16][33], ssp[16][33];
    __shared__ float mu_s[32], rs_s[32];

    size_t base = ((size_t)b * C + cs * 32) * L + l0 + li_;
    const short* otp = ot + base;

    float xr[32];
    float s = 0.f, ss = 0.f;
    #pragma unroll
    for (int cc = 0; cc < 32; cc++) {
        float x = bfs2f(otp[(size_t)cc * L]);
        xr[cc] = x;
        s += x; ss += x * x;
    }
    sp[cs][li_] = s; ssp[cs][li_] = ss;
    __syncthreads();
    if (tid < 32) {
        float t1 = 0.f, t2 = 0.f;
        #pragma unroll
        for (int j = 0; j < 16; j++) { t1 += sp[j][tid]; t2 += ssp[j][tid]; }
        float mean = t1 * (1.f / 512.f);
        float var  = t2 * (1.f / 512.f) - mean * mean;
        mu_s[tid] = mean;
        rs_s[tid] = rsqrtf(var + 1e-5f);
    }
    __syncthreads();
    float mu = mu_s[li_], rs = rs_s[li_];
    float* yp = y + base;
    #pragma unroll
    for (int cc = 0; cc < 32; cc++) {
        int c = cs * 32 + cc;
        yp[(size_t)cc * L] = (xr[cc] - mu) * rs * gamma[c] + beta[c];
    }
}

// ---------------------------------------------------------------------------
extern "C" void kernel_launch(void* const* d_in, const int* in_sizes, int n_in,
                              void* d_out, int out_size, void* d_ws, size_t ws_size,
                              hipStream_t stream)
{
    const float* q     = (const float*)d_in[0];
    const float* k     = (const float*)d_in[1];
    // d_in[2] = mask — analytic
    const float* wq    = (const float*)d_in[3];
    const float* wk    = (const float*)d_in[4];
    const float* wv    = (const float*)d_in[5];
    const float* gamma = (const float*)d_in[6];
    const float* beta  = (const float*)d_in[7];
    float* y = (float*)d_out;

    const size_t N = (size_t)B * H * L * D;      // 4,194,304
    short* kh  = (short*)d_ws;                   // [BH][16][64 rows][8-chunk swz]
    short* vh  = kh + N;                         // [BH][16][d 64][l-chunk swz]
    short* ot  = vh + N;                         // [B, C, L] bf16 (o/L + q)
    short* wtg = ot + N;                         // 294912 bf16 A-frag weights

    wprep_kernel<<<1152, 256, 0, stream>>>(wq, wk, wv, wtg);
    conv_kv_kernel<<<B * H * (L / 64), 256, 0, stream>>>(k, wtg, kh, vh);
    flash_kernel<<<B * H * (L / 64), 256, 0, stream>>>(q, wtg, kh, vh, ot);
    ln_kernel<<<B * (L / 32), 512, 0, stream>>>(ot, gamma, beta, y);
}